// Round 8
// baseline (1358.221 us; speedup 1.0000x reference)
//
#include <hip/hip_runtime.h>
#include <hip/hip_bf16.h>

// ---------------------------------------------------------------------------
// IterativeVoxelModel megakernel. N = 256*27 = 6912 tokens, d=256, heads=8
// (hd=32), ffn=1024. R8: entire 3-layer network in ONE persistent kernel
// (216 blocks = 1/CU, guaranteed co-resident) with atomic grid barriers.
// Eliminates ~22 dispatch boundaries. Stage bodies = R6's verified kernels.
// ---------------------------------------------------------------------------

#define NTOK 6912
#define DM   256
#define FF   1024
#define NB   216     // grid size; 6912/32=216 LN blocks, 54*4=216 d x d tiles

typedef __hip_bfloat16 bf16;
typedef __bf16 bf16x8 __attribute__((ext_vector_type(8)));
typedef float  f32x4  __attribute__((ext_vector_type(4)));

__device__ __forceinline__ void gload_lds16(const void* g, void* l) {
    __builtin_amdgcn_global_load_lds(
        (const __attribute__((address_space(1))) void*)g,
        (__attribute__((address_space(3))) void*)l, 16, 0, 0);
}

__device__ __forceinline__ unsigned short f2bf_bits(float x) {
    bf16 h = __float2bfloat16(x);
    union { bf16 h; unsigned short u; } c; c.h = h; return c.u;
}

// ---- grid barrier: monotonic arrival counter, device-scope, fenced --------
__device__ __forceinline__ void gridbar(int* cnt, int target) {
    __threadfence();                      // release: drain stores, wb L2 (cross-XCD)
    __syncthreads();
    if (threadIdx.x == 0) {
        atomicAdd(cnt, 1);
        while (__hip_atomic_load(cnt, __ATOMIC_RELAXED,
                                 __HIP_MEMORY_SCOPE_AGENT) < target)
            __builtin_amdgcn_s_sleep(2);
    }
    __syncthreads();
    __threadfence();                      // acquire: invalidate stale cache lines
}

// ---- weight convert+transpose jobs: W[K][N] f32 -> Wt[N][K] bf16 ----------
__device__ void convert_stage(
    const float* Wq, const float* Wk, const float* Wv, const float* Wo,
    const float* W1, const float* W2, bf16* Wt, float* tile, int bid)
{
    int tx = threadIdx.x & 31, ty = threadIdx.x >> 5;     // 32 x 8
    for (int j = bid; j < 2304; j += NB) {
        const float* src; bf16* dst; int K, N, n0, k0;
        if (j < 768) {                       // 12 d x d mats, 64 tiles each
            int id = j >> 6, tt = j & 63;
            int l = id >> 2, wsel = id & 3;
            const float* tbl[4] = {Wq, Wk, Wv, Wo};
            src = tbl[wsel] + (size_t)l * 65536;
            dst = Wt + (size_t)l * 786432 + wsel * 65536;
            K = 256; N = 256; n0 = (tt & 7) * 32; k0 = (tt >> 3) * 32;
        } else {                             // 6 big mats, 256 tiles each
            int jb = j - 768, id = jb >> 8, tt = jb & 255;
            int l = id >> 1;
            if ((id & 1) == 0) {             // W1: K=256 -> N=1024
                src = W1 + (size_t)l * 262144;
                dst = Wt + (size_t)l * 786432 + 262144;
                K = 256; N = 1024; n0 = (tt & 31) * 32; k0 = (tt >> 5) * 32;
            } else {                         // W2: K=1024 -> N=256
                src = W2 + (size_t)l * 262144;
                dst = Wt + (size_t)l * 786432 + 524288;
                K = 1024; N = 256; n0 = (tt & 7) * 32; k0 = (tt >> 3) * 32;
            }
        }
        __syncthreads();
#pragma unroll
        for (int i = 0; i < 4; ++i)
            tile[(ty + i * 8) * 33 + tx] =
                src[(size_t)(k0 + ty + i * 8) * N + n0 + tx];
        __syncthreads();
#pragma unroll
        for (int i = 0; i < 4; ++i)
            dst[(size_t)(n0 + ty + i * 8) * K + k0 + tx] =
                __float2bfloat16(tile[tx * 33 + ty + i * 8]);
    }
}

// ---- embed + mask (wave per token, 32 tokens per block) -------------------
__device__ void embed_stage(
    const float* npat, const int* km, const float* w_in, const float* b_in,
    const float* pos, float* t, bf16* t_bf, unsigned int* mask27, int bid)
{
    int wv = threadIdx.x >> 6, ln = threadIdx.x & 63;
    float4 w4 = *(const float4*)&w_in[ln * 4];
    float4 bi4 = *(const float4*)&b_in[ln * 4];
    for (int i = 0; i < 8; ++i) {
        int n = bid * 32 + wv * 8 + i;
        int b = n / 27, q = n - b * 27;
        float nv = npat[n];
        float4 p4 = *(const float4*)&pos[q * DM + ln * 4];
        float4 v;
        v.x = nv * w4.x + bi4.x + p4.x;  v.y = nv * w4.y + bi4.y + p4.y;
        v.z = nv * w4.z + bi4.z + p4.z;  v.w = nv * w4.w + bi4.w + p4.w;
        *(float4*)&t[(size_t)n * DM + ln * 4] = v;
        ushort4 o;
        o.x = f2bf_bits(v.x); o.y = f2bf_bits(v.y);
        o.z = f2bf_bits(v.z); o.w = f2bf_bits(v.w);
        *(ushort4*)&t_bf[(size_t)n * DM + ln * 4] = o;
        bool bit = false;
        if (ln < 27) {
            int zq = q / 9, yq = (q / 3) % 3, xq = q % 3;
            int zm = ln / 9, ym = (ln / 3) % 3, xm = ln % 3;
            bit = (abs(zm - zq) <= 1) && (abs(ym - yq) <= 1) &&
                  (abs(xm - xq) <= 1) && (km[b * 27 + ln] != 0);
        }
        unsigned long long bm = __ballot(bit);
        if (ln == 0) mask27[n] = (unsigned int)(bm & 0x7FFFFFFULL);
    }
}

// ---- layernorm (wave per token, 32 tokens per block) ----------------------
__device__ void ln_stage(const float* X, const float* g, const float* bta,
                         bf16* Y, int bid)
{
    int wv = threadIdx.x >> 6, ln = threadIdx.x & 63;
    float4 g4 = *(const float4*)&g[ln * 4];
    float4 b4 = *(const float4*)&bta[ln * 4];
    for (int i = 0; i < 8; ++i) {
        int n = bid * 32 + wv * 8 + i;
        float4 x4 = *(const float4*)&X[(size_t)n * DM + ln * 4];
        float s = x4.x + x4.y + x4.z + x4.w;
        float s2 = x4.x * x4.x + x4.y * x4.y + x4.z * x4.z + x4.w * x4.w;
        for (int off = 32; off; off >>= 1) {
            s += __shfl_xor(s, off); s2 += __shfl_xor(s2, off);
        }
        float mu = s * (1.0f / DM);
        float var = s2 * (1.0f / DM) - mu * mu;
        float r = rsqrtf(var + 1e-5f);
        ushort4 o;
        o.x = f2bf_bits((x4.x - mu) * r * g4.x + b4.x);
        o.y = f2bf_bits((x4.y - mu) * r * g4.y + b4.y);
        o.z = f2bf_bits((x4.z - mu) * r * g4.z + b4.z);
        o.w = f2bf_bits((x4.w - mu) * r * g4.w + b4.w);
        *(ushort4*)&Y[(size_t)n * DM + ln * 4] = o;
    }
}

// ---- bf16 MFMA GEMM tile (128x64, 4 waves, single-buffer) -----------------
// mode 0: normal epilogue; mode 2: bf16 out transposed per patch.
__device__ void gemm_tile(
    const bf16* A, const bf16* Bt, const float* bias, const float* residual,
    float* Cf, bf16* Cb, int K, int Nc, int act, int mode, int row0, int col0,
    bf16* As, bf16* Bs)
{
    int tid = threadIdx.x;
    int wv = tid >> 6, ln = tid & 63;
    int wr = wv >> 1, wc = wv & 1;

    f32x4 acc[4][2];
#pragma unroll
    for (int m = 0; m < 4; ++m)
#pragma unroll
        for (int n = 0; n < 2; ++n) acc[m][n] = (f32x4){0.f, 0.f, 0.f, 0.f};

    int lrow = ln >> 3;
    int kof  = (ln & 7) * 8;

    for (int k0 = 0; k0 < K; k0 += 64) {
        __syncthreads();
#pragma unroll
        for (int i = 0; i < 4; ++i) {
            int slot = i * 4 + wv;
            gload_lds16(A + (size_t)(row0 + slot * 8 + lrow) * K + k0 + kof,
                        As + slot * 512);
        }
#pragma unroll
        for (int i = 0; i < 2; ++i) {
            int slot = i * 4 + wv;
            gload_lds16(Bt + (size_t)(col0 + slot * 8 + lrow) * K + k0 + kof,
                        Bs + slot * 512);
        }
        __syncthreads();
        int lr = ln & 15, kg = ln >> 4;
#pragma unroll
        for (int kk = 0; kk < 2; ++kk) {
            int koff = kk * 32 + kg * 8;
            bf16x8 a[4], b[2];
#pragma unroll
            for (int m = 0; m < 4; ++m)
                a[m] = *(const bf16x8*)&As[(wr * 64 + m * 16 + lr) * 64 + koff];
#pragma unroll
            for (int n = 0; n < 2; ++n)
                b[n] = *(const bf16x8*)&Bs[(wc * 32 + n * 16 + lr) * 64 + koff];
#pragma unroll
            for (int m = 0; m < 4; ++m)
#pragma unroll
                for (int n = 0; n < 2; ++n)
                    acc[m][n] = __builtin_amdgcn_mfma_f32_16x16x32_bf16(
                        a[m], b[n], acc[m][n], 0, 0, 0);
        }
    }

    int lr = ln & 15, rg = ln >> 4;
#pragma unroll
    for (int m = 0; m < 4; ++m) {
#pragma unroll
        for (int n = 0; n < 2; ++n) {
            int col = col0 + wc * 32 + n * 16 + lr;
            float bcol = bias[col];
#pragma unroll
            for (int r = 0; r < 4; ++r) {
                int row = row0 + wr * 64 + m * 16 + rg * 4 + r;
                float v = acc[m][n][r] + bcol;
                if (mode == 2) {
                    int bb = row / 27, tok = row - bb * 27;
                    Cb[((size_t)bb * DM + col) * 32 + tok] = __float2bfloat16(v);
                } else {
                    size_t idx = (size_t)row * Nc + col;
                    if (residual) v += residual[idx];
                    if (act) v = 0.5f * v * (1.0f + erff(v * 0.70710678118654752f));
                    if (Cf) Cf[idx] = v;
                    if (Cb) Cb[idx] = __float2bfloat16(v);
                }
            }
        }
    }
}

// ---- MFMA attention for one (patch, head-quad) ----------------------------
__device__ void attn_patch(
    const bf16* Qb, const bf16* Kb, const bf16* Vt,
    const unsigned int* mask27, bf16* out, int b, int y, bf16* Pbase)
{
    int wv = threadIdx.x >> 6;
    int head = y * 4 + wv;
    int ln = threadIdx.x & 63;
    int r = ln & 15, g = ln >> 4;
    bf16* P = Pbase + wv * 1280;          // 32*40 per wave

    const bf16* Kp = Kb + (size_t)b * 27 * DM + head * 32;
    const bf16* Qp = Qb + (size_t)b * 27 * DM + head * 32;

    bf16x8 aK[2], bQ[2];
    aK[0] = *(const bf16x8*)(Kp + (size_t)r * DM + g * 8);
    aK[1] = *(const bf16x8*)(Kp + (size_t)(16 + r) * DM + g * 8);
    bQ[0] = *(const bf16x8*)(Qp + (size_t)r * DM + g * 8);
    bQ[1] = *(const bf16x8*)(Qp + (size_t)(16 + r) * DM + g * 8);

    f32x4 acc[2][2];
#pragma unroll
    for (int at = 0; at < 2; ++at)
#pragma unroll
        for (int bt = 0; bt < 2; ++bt)
            acc[at][bt] = __builtin_amdgcn_mfma_f32_16x16x32_bf16(
                aK[at], bQ[bt], (f32x4){0.f, 0.f, 0.f, 0.f}, 0, 0, 0);

    unsigned int Mq[2];
    Mq[0] = mask27[b * 27 + r];
    Mq[1] = (16 + r < 27) ? mask27[b * 27 + 16 + r] : 0u;

#pragma unroll
    for (int bt = 0; bt < 2; ++bt) {
        float e[2][4];
        float mx = -1e30f;
#pragma unroll
        for (int at = 0; at < 2; ++at)
#pragma unroll
            for (int rg = 0; rg < 4; ++rg) {
                int m = at * 16 + g * 4 + rg;
                bool in = (Mq[bt] >> m) & 1;
                float sv = acc[at][bt][rg] * 0.17677669529663687f;
                e[at][rg] = in ? sv : -1e30f;
                mx = fmaxf(mx, e[at][rg]);
            }
        mx = fmaxf(mx, __shfl_xor(mx, 16));
        mx = fmaxf(mx, __shfl_xor(mx, 32));
        float sum = 0.f;
#pragma unroll
        for (int at = 0; at < 2; ++at)
#pragma unroll
            for (int rg = 0; rg < 4; ++rg) {
                int m = at * 16 + g * 4 + rg;
                bool in = (Mq[bt] >> m) & 1;
                float ev = in ? expf(e[at][rg] - mx) : 0.f;
                e[at][rg] = ev;
                sum += ev;
            }
        sum += __shfl_xor(sum, 16);
        sum += __shfl_xor(sum, 32);
        float inv = (sum > 0.f) ? 1.f / sum : 0.f;
#pragma unroll
        for (int at = 0; at < 2; ++at) {
            ushort4 u;
            u.x = f2bf_bits(e[at][0] * inv);
            u.y = f2bf_bits(e[at][1] * inv);
            u.z = f2bf_bits(e[at][2] * inv);
            u.w = f2bf_bits(e[at][3] * inv);
            *(ushort4*)&P[(bt * 16 + r) * 40 + at * 16 + g * 4] = u;
        }
    }

    bf16x8 pa[2], vb[2];
    pa[0] = *(const bf16x8*)&P[(size_t)r * 40 + g * 8];
    pa[1] = *(const bf16x8*)&P[(size_t)(16 + r) * 40 + g * 8];
    const bf16* Vp = Vt + ((size_t)b * DM + head * 32) * 32;
    vb[0] = *(const bf16x8*)(Vp + (size_t)r * 32 + g * 8);
    vb[1] = *(const bf16x8*)(Vp + (size_t)(16 + r) * 32 + g * 8);

    f32x4 o[2][2];
#pragma unroll
    for (int qt = 0; qt < 2; ++qt)
#pragma unroll
        for (int dt = 0; dt < 2; ++dt)
            o[qt][dt] = __builtin_amdgcn_mfma_f32_16x16x32_bf16(
                pa[qt], vb[dt], (f32x4){0.f, 0.f, 0.f, 0.f}, 0, 0, 0);

#pragma unroll
    for (int qt = 0; qt < 2; ++qt)
#pragma unroll
        for (int dt = 0; dt < 2; ++dt)
#pragma unroll
            for (int rg = 0; rg < 4; ++rg) {
                int q = qt * 16 + g * 4 + rg;
                if (q < 27)
                    out[(size_t)(b * 27 + q) * DM + head * 32 + dt * 16 + r] =
                        __float2bfloat16(o[qt][dt][rg]);
            }
}

// ---------------------------------------------------------------------------
__global__ void init_bar(int* bar) { if (threadIdx.x == 0) bar[0] = 0; }

__global__ __launch_bounds__(256) void mega(
    const float* __restrict__ npat, const int* __restrict__ km,
    const float* __restrict__ w_in, const float* __restrict__ b_in,
    const float* __restrict__ pos,
    const float* __restrict__ ln1_g, const float* __restrict__ ln1_b,
    const float* __restrict__ ln2_g, const float* __restrict__ ln2_b,
    const float* __restrict__ Wq, const float* __restrict__ bq,
    const float* __restrict__ Wk, const float* __restrict__ bk,
    const float* __restrict__ Wv, const float* __restrict__ bv,
    const float* __restrict__ Wo, const float* __restrict__ bo,
    const float* __restrict__ W1, const float* __restrict__ b1,
    const float* __restrict__ W2, const float* __restrict__ b2,
    const float* __restrict__ w_out, const float* __restrict__ b_out,
    float* __restrict__ out,
    int* bar, float* t, bf16* t_bf, bf16* tn_bf, bf16* attn_bf,
    bf16* Qb, bf16* Kb, bf16* Vt, bf16* H_bf, bf16* Wt,
    unsigned int* mask27)
{
    __shared__ __align__(16) char smem[24576];
    bf16* As = (bf16*)smem;              // 128*64 = 16 KB
    bf16* Bs = (bf16*)(smem + 16384);    //  64*64 =  8 KB
    int bid = blockIdx.x;
    int epoch = 0;
#define BAR() do { ++epoch; gridbar(bar, epoch * NB); } while (0)

    // stage A: weight convert + embed + mask
    convert_stage(Wq, Wk, Wv, Wo, W1, W2, Wt, (float*)smem, bid);
    embed_stage(npat, km, w_in, b_in, pos, t, t_bf, mask27, bid);
    BAR();

    int bx = bid % 54, ycol = bid / 54;  // d x d tile coords (216 = 54*4)

    for (int l = 0; l < 3; ++l) {
        const bf16* wqt = Wt + (size_t)l * 786432;
        const bf16* wkt = wqt + 65536;
        const bf16* wvt = wkt + 65536;
        const bf16* wot = wvt + 65536;
        const bf16* w1t = wot + 65536;
        const bf16* w2t = w1t + 262144;

        ln_stage(t, ln1_g + l * DM, ln1_b + l * DM, tn_bf, bid);
        BAR();

        gemm_tile(tn_bf, wqt, bq + l * DM, nullptr, nullptr, Qb,
                  256, 256, 0, 0, bx * 128, ycol * 64, As, Bs);
        gemm_tile(t_bf,  wkt, bk + l * DM, nullptr, nullptr, Kb,
                  256, 256, 0, 0, bx * 128, ycol * 64, As, Bs);
        gemm_tile(t_bf,  wvt, bv + l * DM, nullptr, nullptr, Vt,
                  256, 256, 0, 2, bx * 128, ycol * 64, As, Bs);
        BAR();

        for (int p = bid; p < 256; p += NB)
            for (int y = 0; y < 2; ++y)
                attn_patch(Qb, Kb, Vt, mask27, attn_bf, p, y, (bf16*)smem);
        BAR();

        gemm_tile(attn_bf, wot, bo + l * DM, t, t, t_bf,
                  256, 256, 0, 0, bx * 128, ycol * 64, As, Bs);
        BAR();

        ln_stage(t, ln2_g + l * DM, ln2_b + l * DM, tn_bf, bid);
        BAR();

        for (int i = 0; i < 4; ++i) {
            int vb = i * NB + bid;               // 0..863
            int fx = vb % 54, fy = vb / 54;      // fy 0..15
            gemm_tile(tn_bf, w1t, b1 + l * FF, nullptr, nullptr, H_bf,
                      256, 1024, 1, 0, fx * 128, fy * 64, As, Bs);
        }
        BAR();

        gemm_tile(H_bf, w2t, b2 + l * DM, t, t, t_bf,
                  1024, 256, 0, 0, bx * 128, ycol * 64, As, Bs);
        BAR();
    }

    // out_proj: wave per output patch
    {
        int wv = threadIdx.x >> 6, ln = threadIdx.x & 63;
        int b = wv * NB + bid;
        if (b < 256) {
            float4 x4 = *(const float4*)&t[(size_t)(b * 27 + 13) * DM + ln * 4];
            float4 w4 = *(const float4*)&w_out[ln * 4];
            float v = x4.x * w4.x + x4.y * w4.y + x4.z * w4.z + x4.w * w4.w;
            for (int off = 32; off; off >>= 1) v += __shfl_xor(v, off);
            if (ln == 0) out[b] = v + b_out[0];
        }
    }
#undef BAR
}

// ---------------------------------------------------------------------------
extern "C" void kernel_launch(void* const* d_in, const int* in_sizes, int n_in,
                              void* d_out, int out_size, void* d_ws, size_t ws_size,
                              hipStream_t stream)
{
    const float* npat  = (const float*)d_in[0];
    const int*   kmask = (const int*)  d_in[1];
    const float* w_in  = (const float*)d_in[2];
    const float* b_in  = (const float*)d_in[3];
    const float* pos   = (const float*)d_in[4];
    const float* ln1_g = (const float*)d_in[5];
    const float* ln1_b = (const float*)d_in[6];
    const float* ln2_g = (const float*)d_in[7];
    const float* ln2_b = (const float*)d_in[8];
    const float* Wq    = (const float*)d_in[9];
    const float* bq    = (const float*)d_in[10];
    const float* Wk    = (const float*)d_in[11];
    const float* bk    = (const float*)d_in[12];
    const float* Wv    = (const float*)d_in[13];
    const float* bv    = (const float*)d_in[14];
    const float* Wo    = (const float*)d_in[15];
    const float* bo    = (const float*)d_in[16];
    const float* W1    = (const float*)d_in[17];
    const float* b1    = (const float*)d_in[18];
    const float* W2    = (const float*)d_in[19];
    const float* b2    = (const float*)d_in[20];
    const float* w_out = (const float*)d_in[21];
    const float* b_out = (const float*)d_in[22];
    float* out = (float*)d_out;

    // workspace carve-up (offsets multiples of 256B)
    char* ws = (char*)d_ws;
    int* bar = (int*)ws;
    char* p = ws + 256;
    float* t = (float*)p;                    p += (size_t)NTOK * DM * 4;
    bf16* t_bf    = (bf16*)p;                p += (size_t)NTOK * DM * 2;
    bf16* tn_bf   = (bf16*)p;                p += (size_t)NTOK * DM * 2;
    bf16* attn_bf = (bf16*)p;                p += (size_t)NTOK * DM * 2;
    bf16* Qb      = (bf16*)p;                p += (size_t)NTOK * DM * 2;
    bf16* Kb      = (bf16*)p;                p += (size_t)NTOK * DM * 2;  // attn over-read -> Vt: safe
    bf16* Vt      = (bf16*)p;                p += (size_t)256 * DM * 32 * 2;
    bf16* H_bf    = (bf16*)p;                p += (size_t)NTOK * FF * 2;
    bf16* Wt      = (bf16*)p;                p += (size_t)3 * 786432 * 2;
    unsigned int* mask27 = (unsigned int*)p;

    init_bar<<<1, 64, 0, stream>>>(bar);
    mega<<<NB, 256, 0, stream>>>(
        npat, kmask, w_in, b_in, pos, ln1_g, ln1_b, ln2_g, ln2_b,
        Wq, bq, Wk, bk, Wv, bv, Wo, bo, W1, b1, W2, b2, w_out, b_out, out,
        bar, t, t_bf, tn_bf, attn_bf, Qb, Kb, Vt, H_bf, Wt, mask27);
}

// Round 10
// 403.417 us; speedup vs baseline: 3.3668x; 3.3668x over previous
//
#include <hip/hip_runtime.h>
#include <hip/hip_bf16.h>

// ---------------------------------------------------------------------------
// IterativeVoxelModel R9 (resubmit after infra timeout): whole-network-per-
// patch kernel. The 3x3x3 attention window never crosses patch boundaries,
// so after embed each patch's 27 tokens are fully independent through all 3
// layers. One block (512 thr, 8 waves) per patch; residual t in registers
// (16 f32/thread), activations in swizzled LDS, weights streamed from L2
// straight into MFMA B-fragments. No grid sync, no fences, 2 dispatches.
// ---------------------------------------------------------------------------

#define NTOK 6912
#define DM   256
#define FF   1024

typedef __hip_bfloat16 bf16;
typedef __bf16 bf16x8 __attribute__((ext_vector_type(8)));
typedef float  f32x4  __attribute__((ext_vector_type(4)));

__device__ __forceinline__ unsigned short f2bf_bits(float x) {
    bf16 h = __float2bfloat16(x);
    union { bf16 h; unsigned short u; } u2; u2.h = h; return u2.u;
}

// row-major [32][rowB bytes] LDS buffer with XOR swizzle on 16B granules
// (breaks the 16-lanes-same-bank pattern of 512B/2048B row strides).
__device__ __forceinline__ bf16x8 ldsA(const char* buf, int row, int kbyte, int rowB) {
    return *(const bf16x8*)(buf + row * rowB + (kbyte ^ ((row & 7) << 4)));
}
__device__ __forceinline__ void ldsW(char* buf, int row, int col, int rowB, float v) {
    *(unsigned short*)(buf + row * rowB + ((col * 2) ^ ((row & 7) << 4))) = f2bf_bits(v);
}

// ---------------- weight convert+transpose: W[K][N] f32 -> Wt[N][K] bf16 ---
__global__ __launch_bounds__(256) void convert_weights(
    const float* __restrict__ Wq, const float* __restrict__ Wk,
    const float* __restrict__ Wv, const float* __restrict__ Wo,
    const float* __restrict__ W1, const float* __restrict__ W2,
    bf16* __restrict__ Wt)
{
    __shared__ float tile[32][33];
    int id = blockIdx.z;
    int l = id / 6, wsel = id % 6;
    const float* src; bf16* dst; int K, N;
    if (wsel < 4) {
        const float* tbl[4] = {Wq, Wk, Wv, Wo};
        src = tbl[wsel] + (size_t)l * 65536; K = 256; N = 256;
        dst = Wt + (size_t)l * 786432 + wsel * 65536;
    } else if (wsel == 4) {
        src = W1 + (size_t)l * 262144; K = 256; N = 1024;
        dst = Wt + (size_t)l * 786432 + 262144;
    } else {
        src = W2 + (size_t)l * 262144; K = 1024; N = 256;
        dst = Wt + (size_t)l * 786432 + 524288;
    }
    int n0 = blockIdx.x * 32, k0 = blockIdx.y * 32;
    if (n0 >= N || k0 >= K) return;
    int tx = threadIdx.x, ty = threadIdx.y;   // 32 x 8
#pragma unroll
    for (int i = 0; i < 4; ++i)
        tile[ty + i * 8][tx] = src[(size_t)(k0 + ty + i * 8) * N + n0 + tx];
    __syncthreads();
#pragma unroll
    for (int i = 0; i < 4; ++i)
        dst[(size_t)(n0 + ty + i * 8) * K + k0 + tx] =
            __float2bfloat16(tile[tx][ty + i * 8]);
}

// ---- GEMM: out[32 tokens][32-col slice] = A_lds[32][K] @ Bt[N][K]^T -------
// A from swizzled LDS; B streamed global->reg (16B/lane, 64B-line coalesced).
template<int K, int ROWB>
__device__ __forceinline__ void gemm32(const char* A, const bf16* __restrict__ Bt,
                                       int wva, int c, int g, f32x4 acc[2][2])
{
#pragma unroll
    for (int m = 0; m < 2; ++m)
#pragma unroll
        for (int n = 0; n < 2; ++n) acc[m][n] = (f32x4){0.f, 0.f, 0.f, 0.f};
#pragma unroll
    for (int ks = 0; ks < K / 32; ++ks) {
        bf16x8 a0 = ldsA(A, c,      ks * 64 + g * 16, ROWB);
        bf16x8 a1 = ldsA(A, 16 + c, ks * 64 + g * 16, ROWB);
        const bf16* bp = Bt + (size_t)(wva * 32 + c) * K + ks * 32 + g * 8;
        bf16x8 b0 = *(const bf16x8*)bp;
        bf16x8 b1 = *(const bf16x8*)(bp + (size_t)16 * K);
        acc[0][0] = __builtin_amdgcn_mfma_f32_16x16x32_bf16(a0, b0, acc[0][0], 0, 0, 0);
        acc[0][1] = __builtin_amdgcn_mfma_f32_16x16x32_bf16(a0, b1, acc[0][1], 0, 0, 0);
        acc[1][0] = __builtin_amdgcn_mfma_f32_16x16x32_bf16(a1, b0, acc[1][0], 0, 0, 0);
        acc[1][1] = __builtin_amdgcn_mfma_f32_16x16x32_bf16(a1, b1, acc[1][1], 0, 0, 0);
    }
}

// ---- LN row stats from register-resident residual ------------------------
__device__ __forceinline__ void ln_stats(const float tr[2][2][4], int wva, int c, int g,
                                         float* red, float* red2,
                                         float mu[2][4], float rr[2][4])
{
#pragma unroll
    for (int m = 0; m < 2; ++m)
#pragma unroll
    for (int j = 0; j < 4; ++j) {
        float s = tr[m][0][j] + tr[m][1][j];
        float q = tr[m][0][j] * tr[m][0][j] + tr[m][1][j] * tr[m][1][j];
#pragma unroll
        for (int off = 1; off < 16; off <<= 1) {
            s += __shfl_xor(s, off); q += __shfl_xor(q, off);
        }
        if (c == 0) { int row = m * 16 + g * 4 + j; red[row * 12 + wva] = s; red2[row * 12 + wva] = q; }
    }
    __syncthreads();
#pragma unroll
    for (int m = 0; m < 2; ++m)
#pragma unroll
    for (int j = 0; j < 4; ++j) {
        int row = m * 16 + g * 4 + j;
        float S = 0.f, Q = 0.f;
#pragma unroll
        for (int w = 0; w < 8; ++w) { S += red[row * 12 + w]; Q += red2[row * 12 + w]; }
        float m_ = S * (1.0f / DM);
        float v_ = Q * (1.0f / DM) - m_ * m_;
        mu[m][j] = m_; rr[m][j] = rsqrtf(v_ + 1e-5f);
    }
}

// ---------------------------------------------------------------------------
__global__ __launch_bounds__(512, 2) void patch_net(
    const float* __restrict__ npat, const int* __restrict__ km,
    const float* __restrict__ w_in, const float* __restrict__ b_in,
    const float* __restrict__ pos,
    const float* __restrict__ ln1g, const float* __restrict__ ln1b,
    const float* __restrict__ ln2g, const float* __restrict__ ln2b,
    const float* __restrict__ bq, const float* __restrict__ bk,
    const float* __restrict__ bv, const float* __restrict__ bo,
    const float* __restrict__ b1, const float* __restrict__ b2,
    const float* __restrict__ w_out, const float* __restrict__ b_out,
    const bf16* __restrict__ Wt, float* __restrict__ out)
{
    // LDS map. region0 (0..69632) is {T_bf,Q,K,Vt} during attn phases and
    // H[32][1024] during FFN (all four are dead there).
    __shared__ __align__(16) char L[110592];
    char* Tbf = L;                  // [32][256] bf16 swz
    char* Qb  = L + 16384;
    char* Kb  = L + 32768;
    char* Vt  = L + 49152;          // [256][40] ushort (d-major, m contiguous)
    char* Hb  = L;                  // [32][1024] bf16 swz (FFN phase)
    char* TnA = L + 69632;          // LN1-out / attn-O / LN2-out
    char* Pb  = L + 86016;          // 8 waves x [32][40] ushort
    float* red  = (float*)(L + 106496);
    float* red2 = (float*)(L + 108032);
    unsigned* kbits_p = (unsigned*)(L + 109568);

    int p = blockIdx.x;
    int tid = threadIdx.x;
    int wva = tid >> 6, ln = tid & 63;
    int c = ln & 15, g = ln >> 4;

    // 27-bit geometric window masks for this lane's two query tokens
    unsigned win0 = 0, win1 = 0;
    {
        int zq0 = c / 9, yq0 = (c / 3) % 3, xq0 = c % 3;
        int q1 = 16 + c, zq1 = q1 / 9, yq1 = (q1 / 3) % 3, xq1 = q1 % 3;
        for (int m = 0; m < 27; ++m) {
            int zm = m / 9, ym = (m / 3) % 3, xm = m % 3;
            if (abs(zm - zq0) <= 1 && abs(ym - yq0) <= 1 && abs(xm - xq0) <= 1) win0 |= 1u << m;
            if (q1 < 27 && abs(zm - zq1) <= 1 && abs(ym - yq1) <= 1 && abs(xm - xq1) <= 1) win1 |= 1u << m;
        }
    }
    if (tid < 64) {
        bool bit = (tid < 27) && (km[p * 27 + tid] != 0);
        unsigned long long bm = __ballot(bit);
        if (tid == 0) *kbits_p = (unsigned)(bm & 0x7FFFFFFull);
    }

    // ---- embed: residual t in regs (rows m*16+g*4+j, cols wva*32+n*16+c)
    float tr[2][2][4];
#pragma unroll
    for (int m = 0; m < 2; ++m)
#pragma unroll
    for (int j = 0; j < 4; ++j) {
        int row = m * 16 + g * 4 + j;
        float nv = (row < 27) ? npat[p * 27 + row] : 0.f;
#pragma unroll
        for (int n = 0; n < 2; ++n) {
            int col = wva * 32 + n * 16 + c;
            float v = 0.f;
            if (row < 27) v = nv * w_in[col] + b_in[col] + pos[row * DM + col];
            tr[m][n][j] = v;
            ldsW(Tbf, row, col, 512, v);
        }
    }

    f32x4 acc[2][2];
    float mu[2][4], rr[2][4];

    for (int l = 0; l < 3; ++l) {
        const bf16* wq  = Wt + (size_t)l * 786432;
        const bf16* wk  = wq + 65536;
        const bf16* wv2 = wk + 65536;
        const bf16* wo  = wv2 + 65536;
        const bf16* w1  = wo + 65536;
        const bf16* w2  = w1 + 262144;

        // ---- LN1 -> TnA
        ln_stats(tr, wva, c, g, red, red2, mu, rr);
#pragma unroll
        for (int m = 0; m < 2; ++m)
#pragma unroll
        for (int j = 0; j < 4; ++j) {
            int row = m * 16 + g * 4 + j;
#pragma unroll
            for (int n = 0; n < 2; ++n) {
                int col = wva * 32 + n * 16 + c;
                float v = (tr[m][n][j] - mu[m][j]) * rr[m][j] * ln1g[l * DM + col] + ln1b[l * DM + col];
                ldsW(TnA, row, col, 512, v);
            }
        }
        __syncthreads();

        // ---- Q, K, V projections (V stored transposed: Vt[d][m])
        gemm32<256, 512>(TnA, wq, wva, c, g, acc);
#pragma unroll
        for (int m = 0; m < 2; ++m)
#pragma unroll
        for (int n = 0; n < 2; ++n) {
            int col = wva * 32 + n * 16 + c; float bb = bq[l * DM + col];
#pragma unroll
            for (int j = 0; j < 4; ++j) ldsW(Qb, m * 16 + g * 4 + j, col, 512, acc[m][n][j] + bb);
        }
        gemm32<256, 512>(Tbf, wk, wva, c, g, acc);
#pragma unroll
        for (int m = 0; m < 2; ++m)
#pragma unroll
        for (int n = 0; n < 2; ++n) {
            int col = wva * 32 + n * 16 + c; float bb = bk[l * DM + col];
#pragma unroll
            for (int j = 0; j < 4; ++j) ldsW(Kb, m * 16 + g * 4 + j, col, 512, acc[m][n][j] + bb);
        }
        gemm32<256, 512>(Tbf, wv2, wva, c, g, acc);
#pragma unroll
        for (int m = 0; m < 2; ++m)
#pragma unroll
        for (int n = 0; n < 2; ++n) {
            int col = wva * 32 + n * 16 + c; float bb = bv[l * DM + col];
#pragma unroll
            for (int j = 0; j < 4; ++j)
                *(unsigned short*)(Vt + col * 80 + (m * 16 + g * 4 + j) * 2) =
                    f2bf_bits(acc[m][n][j] + bb);
        }
        __syncthreads();

        // ---- attention: wave = head; S^T = K·Q^T; softmax lane-local; O=P·V
        {
            int h = wva;
            bf16x8 aK[2], bQ[2];
#pragma unroll
            for (int m = 0; m < 2; ++m) aK[m] = ldsA(Kb, m * 16 + c, h * 64 + g * 16, 512);
#pragma unroll
            for (int q = 0; q < 2; ++q) bQ[q] = ldsA(Qb, q * 16 + c, h * 64 + g * 16, 512);
            f32x4 sA[2][2];
#pragma unroll
            for (int at = 0; at < 2; ++at)
#pragma unroll
            for (int bt = 0; bt < 2; ++bt)
                sA[at][bt] = __builtin_amdgcn_mfma_f32_16x16x32_bf16(
                    aK[at], bQ[bt], (f32x4){0.f, 0.f, 0.f, 0.f}, 0, 0, 0);

            unsigned kb = *kbits_p;
            unsigned Mq[2] = { kb & win0, kb & win1 };
            char* Pw = Pb + wva * 2560;
#pragma unroll
            for (int bt = 0; bt < 2; ++bt) {
                float e[2][4];
                float mx = -1e30f;
#pragma unroll
                for (int at = 0; at < 2; ++at)
#pragma unroll
                for (int rg = 0; rg < 4; ++rg) {
                    int m = at * 16 + g * 4 + rg;
                    bool in = (Mq[bt] >> m) & 1;
                    float sv = sA[at][bt][rg] * 0.17677669529663687f;
                    e[at][rg] = in ? sv : -1e30f;
                    mx = fmaxf(mx, e[at][rg]);
                }
                mx = fmaxf(mx, __shfl_xor(mx, 16));
                mx = fmaxf(mx, __shfl_xor(mx, 32));
                float sum = 0.f;
#pragma unroll
                for (int at = 0; at < 2; ++at)
#pragma unroll
                for (int rg = 0; rg < 4; ++rg) {
                    int m = at * 16 + g * 4 + rg;
                    bool in = (Mq[bt] >> m) & 1;
                    float ev = in ? expf(e[at][rg] - mx) : 0.f;
                    e[at][rg] = ev; sum += ev;
                }
                sum += __shfl_xor(sum, 16);
                sum += __shfl_xor(sum, 32);
                float inv = (sum > 0.f) ? 1.f / sum : 0.f;
#pragma unroll
                for (int at = 0; at < 2; ++at) {
                    ushort4 u;
                    u.x = f2bf_bits(e[at][0] * inv); u.y = f2bf_bits(e[at][1] * inv);
                    u.z = f2bf_bits(e[at][2] * inv); u.w = f2bf_bits(e[at][3] * inv);
                    *(ushort4*)(Pw + (bt * 16 + c) * 80 + (at * 16 + g * 4) * 2) = u;
                }
            }
            // PV (DS ops are in-order per wave: no barrier needed on Pw)
            bf16x8 pa[2], vb[2];
#pragma unroll
            for (int qt = 0; qt < 2; ++qt) pa[qt] = *(const bf16x8*)(Pw + (qt * 16 + c) * 80 + g * 16);
#pragma unroll
            for (int dt = 0; dt < 2; ++dt)
                vb[dt] = *(const bf16x8*)(Vt + (h * 32 + dt * 16 + c) * 80 + g * 16);
            f32x4 o[2][2];
#pragma unroll
            for (int qt = 0; qt < 2; ++qt)
#pragma unroll
            for (int dt = 0; dt < 2; ++dt)
                o[qt][dt] = __builtin_amdgcn_mfma_f32_16x16x32_bf16(
                    pa[qt], vb[dt], (f32x4){0.f, 0.f, 0.f, 0.f}, 0, 0, 0);
#pragma unroll
            for (int qt = 0; qt < 2; ++qt)
#pragma unroll
            for (int dt = 0; dt < 2; ++dt)
#pragma unroll
            for (int rg = 0; rg < 4; ++rg)
                ldsW(TnA, qt * 16 + g * 4 + rg, h * 32 + dt * 16 + c, 512, o[qt][dt][rg]);
        }
        __syncthreads();

        // ---- Wo + residual into regs
        gemm32<256, 512>(TnA, wo, wva, c, g, acc);
#pragma unroll
        for (int m = 0; m < 2; ++m)
#pragma unroll
        for (int n = 0; n < 2; ++n) {
            int col = wva * 32 + n * 16 + c; float bb = bo[l * DM + col];
#pragma unroll
            for (int j = 0; j < 4; ++j) tr[m][n][j] += acc[m][n][j] + bb;
        }

        // ---- LN2 -> TnA (internal syncthreads also fences Wo's TnA reads)
        ln_stats(tr, wva, c, g, red, red2, mu, rr);
#pragma unroll
        for (int m = 0; m < 2; ++m)
#pragma unroll
        for (int j = 0; j < 4; ++j) {
            int row = m * 16 + g * 4 + j;
#pragma unroll
            for (int n = 0; n < 2; ++n) {
                int col = wva * 32 + n * 16 + c;
                float v = (tr[m][n][j] - mu[m][j]) * rr[m][j] * ln2g[l * DM + col] + ln2b[l * DM + col];
                ldsW(TnA, row, col, 512, v);
            }
        }
        __syncthreads();

        // ---- FFN1: H = gelu(Tn2 @ W1 + b1); wave slice = 128 cols
        {
            f32x4 a8[2][8];
#pragma unroll
            for (int m = 0; m < 2; ++m)
#pragma unroll
            for (int n = 0; n < 8; ++n) a8[m][n] = (f32x4){0.f, 0.f, 0.f, 0.f};
#pragma unroll
            for (int ks = 0; ks < 8; ++ks) {
                bf16x8 a0 = ldsA(TnA, c,      ks * 64 + g * 16, 512);
                bf16x8 a1 = ldsA(TnA, 16 + c, ks * 64 + g * 16, 512);
#pragma unroll
                for (int n = 0; n < 8; ++n) {
                    const bf16* bp = w1 + (size_t)(wva * 128 + n * 16 + c) * 256 + ks * 32 + g * 8;
                    bf16x8 b0 = *(const bf16x8*)bp;
                    a8[0][n] = __builtin_amdgcn_mfma_f32_16x16x32_bf16(a0, b0, a8[0][n], 0, 0, 0);
                    a8[1][n] = __builtin_amdgcn_mfma_f32_16x16x32_bf16(a1, b0, a8[1][n], 0, 0, 0);
                }
            }
#pragma unroll
            for (int m = 0; m < 2; ++m)
#pragma unroll
            for (int n = 0; n < 8; ++n) {
                int col = wva * 128 + n * 16 + c;
                float bb = b1[l * FF + col];
#pragma unroll
                for (int j = 0; j < 4; ++j) {
                    float v = a8[m][n][j] + bb;
                    v = 0.5f * v * (1.0f + erff(v * 0.70710678118654752f));
                    ldsW(Hb, m * 16 + g * 4 + j, col, 2048, v);
                }
            }
        }
        __syncthreads();

        // ---- FFN2 + residual
        gemm32<1024, 2048>(Hb, w2, wva, c, g, acc);
#pragma unroll
        for (int m = 0; m < 2; ++m)
#pragma unroll
        for (int n = 0; n < 2; ++n) {
            int col = wva * 32 + n * 16 + c; float bb = b2[l * DM + col];
#pragma unroll
            for (int j = 0; j < 4; ++j) tr[m][n][j] += acc[m][n][j] + bb;
        }
        __syncthreads();   // all waves done reading H before T_bf overwrite

        // refresh T_bf for next layer (overlaps H rows 0-7, now dead)
#pragma unroll
        for (int m = 0; m < 2; ++m)
#pragma unroll
        for (int j = 0; j < 4; ++j) {
            int row = m * 16 + g * 4 + j;
#pragma unroll
            for (int n = 0; n < 2; ++n)
                ldsW(Tbf, row, wva * 32 + n * 16 + c, 512, tr[m][n][j]);
        }
        __syncthreads();
    }

    // ---- output: out[p] = t[13] . w_out + b_out   (row 13 = m0,g3,j1)
    float v = 0.f;
    if (g == 3) {
        v = tr[0][0][1] * w_out[wva * 32 + c] + tr[0][1][1] * w_out[wva * 32 + 16 + c];
    }
#pragma unroll
    for (int off = 1; off < 16; off <<= 1) v += __shfl_xor(v, off);
    if (ln == 48) red[wva] = v;
    __syncthreads();
    if (tid == 0) {
        float s = 0.f;
#pragma unroll
        for (int w = 0; w < 8; ++w) s += red[w];
        out[p] = s + b_out[0];
    }
}

// ---------------------------------------------------------------------------
extern "C" void kernel_launch(void* const* d_in, const int* in_sizes, int n_in,
                              void* d_out, int out_size, void* d_ws, size_t ws_size,
                              hipStream_t stream)
{
    const float* npat  = (const float*)d_in[0];
    const int*   kmask = (const int*)  d_in[1];
    const float* w_in  = (const float*)d_in[2];
    const float* b_in  = (const float*)d_in[3];
    const float* pos   = (const float*)d_in[4];
    const float* ln1_g = (const float*)d_in[5];
    const float* ln1_b = (const float*)d_in[6];
    const float* ln2_g = (const float*)d_in[7];
    const float* ln2_b = (const float*)d_in[8];
    const float* Wq    = (const float*)d_in[9];
    const float* bq    = (const float*)d_in[10];
    const float* Wk    = (const float*)d_in[11];
    const float* bk    = (const float*)d_in[12];
    const float* Wv    = (const float*)d_in[13];
    const float* bv    = (const float*)d_in[14];
    const float* Wo    = (const float*)d_in[15];
    const float* bo    = (const float*)d_in[16];
    const float* W1    = (const float*)d_in[17];
    const float* b1    = (const float*)d_in[18];
    const float* W2    = (const float*)d_in[19];
    const float* b2    = (const float*)d_in[20];
    const float* w_out = (const float*)d_in[21];
    const float* b_out = (const float*)d_in[22];
    float* out = (float*)d_out;

    bf16* Wt = (bf16*)d_ws;   // 3 * 786432 bf16 = 4.5 MB

    convert_weights<<<dim3(32, 32, 18), dim3(32, 8), 0, stream>>>(
        Wq, Wk, Wv, Wo, W1, W2, Wt);
    patch_net<<<256, 512, 0, stream>>>(
        npat, kmask, w_in, b_in, pos, ln1_g, ln1_b, ln2_g, ln2_b,
        bq, bk, bv, bo, b1, b2, w_out, b_out, Wt, out);
}

// Round 11
// 394.695 us; speedup vs baseline: 3.4412x; 1.0221x over previous
//
#include <hip/hip_runtime.h>
#include <hip/hip_bf16.h>

// ---------------------------------------------------------------------------
// IterativeVoxelModel R11: whole-network-per-patch kernel (R9 structure) with
// BATCHED weight prefetch: every GEMM stage loads all its B-fragments into
// register arrays before the MFMA cluster, exposing ~1 memory latency per
// stage instead of ~16 serialized ones (R9 was latency-bound: MfmaUtil 5%,
// VALUBusy 11%, HBM 8%).
// ---------------------------------------------------------------------------

#define NTOK 6912
#define DM   256
#define FF   1024

typedef __hip_bfloat16 bf16;
typedef __bf16 bf16x8 __attribute__((ext_vector_type(8)));
typedef float  f32x4  __attribute__((ext_vector_type(4)));

#define MFMA16(a, b, c) __builtin_amdgcn_mfma_f32_16x16x32_bf16((a), (b), (c), 0, 0, 0)

__device__ __forceinline__ unsigned short f2bf_bits(float x) {
    bf16 h = __float2bfloat16(x);
    union { bf16 h; unsigned short u; } u2; u2.h = h; return u2.u;
}

// row-major [32][rowB bytes] LDS buffer with XOR swizzle on 16B granules
__device__ __forceinline__ bf16x8 ldsA(const char* buf, int row, int kbyte, int rowB) {
    return *(const bf16x8*)(buf + row * rowB + (kbyte ^ ((row & 7) << 4)));
}
__device__ __forceinline__ void ldsW(char* buf, int row, int col, int rowB, float v) {
    *(unsigned short*)(buf + row * rowB + ((col * 2) ^ ((row & 7) << 4))) = f2bf_bits(v);
}

// ---------------- weight convert+transpose: W[K][N] f32 -> Wt[N][K] bf16 ---
__global__ __launch_bounds__(256) void convert_weights(
    const float* __restrict__ Wq, const float* __restrict__ Wk,
    const float* __restrict__ Wv, const float* __restrict__ Wo,
    const float* __restrict__ W1, const float* __restrict__ W2,
    bf16* __restrict__ Wt)
{
    __shared__ float tile[32][33];
    int id = blockIdx.z;
    int l = id / 6, wsel = id % 6;
    const float* src; bf16* dst; int K, N;
    if (wsel < 4) {
        const float* tbl[4] = {Wq, Wk, Wv, Wo};
        src = tbl[wsel] + (size_t)l * 65536; K = 256; N = 256;
        dst = Wt + (size_t)l * 786432 + wsel * 65536;
    } else if (wsel == 4) {
        src = W1 + (size_t)l * 262144; K = 256; N = 1024;
        dst = Wt + (size_t)l * 786432 + 262144;
    } else {
        src = W2 + (size_t)l * 262144; K = 1024; N = 256;
        dst = Wt + (size_t)l * 786432 + 524288;
    }
    int n0 = blockIdx.x * 32, k0 = blockIdx.y * 32;
    if (n0 >= N || k0 >= K) return;
    int tx = threadIdx.x, ty = threadIdx.y;   // 32 x 8
#pragma unroll
    for (int i = 0; i < 4; ++i)
        tile[ty + i * 8][tx] = src[(size_t)(k0 + ty + i * 8) * N + n0 + tx];
    __syncthreads();
#pragma unroll
    for (int i = 0; i < 4; ++i)
        dst[(size_t)(n0 + ty + i * 8) * K + k0 + tx] =
            __float2bfloat16(tile[tx][ty + i * 8]);
}

// ---- GEMM chunk: acc += A_lds[32 rows][32*NKS k] @ Bt-slice ---------------
// ALL B fragments batch-loaded first (2*NKS global loads in flight), then
// the MFMA cluster: one exposed memory latency per chunk.
template<int NKS, int ROWB>
__device__ __forceinline__ void gemm32_acc(const char* A, int kbyte0,
    const bf16* __restrict__ Bt, int Krow, int k0,
    int wva, int c, int g, f32x4 acc[2][2])
{
    bf16x8 B0[NKS], B1[NKS];
#pragma unroll
    for (int ks = 0; ks < NKS; ++ks) {
        const bf16* bp = Bt + (size_t)(wva * 32 + c) * Krow + k0 + ks * 32 + g * 8;
        B0[ks] = *(const bf16x8*)bp;
        B1[ks] = *(const bf16x8*)(bp + (size_t)16 * Krow);
    }
#pragma unroll
    for (int ks = 0; ks < NKS; ++ks) {
        bf16x8 a0 = ldsA(A, c,      kbyte0 + ks * 64 + g * 16, ROWB);
        bf16x8 a1 = ldsA(A, 16 + c, kbyte0 + ks * 64 + g * 16, ROWB);
        acc[0][0] = MFMA16(a0, B0[ks], acc[0][0]);
        acc[0][1] = MFMA16(a0, B1[ks], acc[0][1]);
        acc[1][0] = MFMA16(a1, B0[ks], acc[1][0]);
        acc[1][1] = MFMA16(a1, B1[ks], acc[1][1]);
    }
}

__device__ __forceinline__ void zero_acc(f32x4 acc[2][2]) {
#pragma unroll
    for (int m = 0; m < 2; ++m)
#pragma unroll
        for (int n = 0; n < 2; ++n) acc[m][n] = (f32x4){0.f, 0.f, 0.f, 0.f};
}

// ---- LN row stats from register-resident residual ------------------------
__device__ __forceinline__ void ln_stats(const float tr[2][2][4], int wva, int c, int g,
                                         float* red, float* red2,
                                         float mu[2][4], float rr[2][4])
{
#pragma unroll
    for (int m = 0; m < 2; ++m)
#pragma unroll
    for (int j = 0; j < 4; ++j) {
        float s = tr[m][0][j] + tr[m][1][j];
        float q = tr[m][0][j] * tr[m][0][j] + tr[m][1][j] * tr[m][1][j];
#pragma unroll
        for (int off = 1; off < 16; off <<= 1) {
            s += __shfl_xor(s, off); q += __shfl_xor(q, off);
        }
        if (c == 0) { int row = m * 16 + g * 4 + j; red[row * 12 + wva] = s; red2[row * 12 + wva] = q; }
    }
    __syncthreads();
#pragma unroll
    for (int m = 0; m < 2; ++m)
#pragma unroll
    for (int j = 0; j < 4; ++j) {
        int row = m * 16 + g * 4 + j;
        float S = 0.f, Q = 0.f;
#pragma unroll
        for (int w = 0; w < 8; ++w) { S += red[row * 12 + w]; Q += red2[row * 12 + w]; }
        float m_ = S * (1.0f / DM);
        float v_ = Q * (1.0f / DM) - m_ * m_;
        mu[m][j] = m_; rr[m][j] = rsqrtf(v_ + 1e-5f);
    }
}

// ---------------------------------------------------------------------------
__global__ __launch_bounds__(512) void patch_net(
    const float* __restrict__ npat, const int* __restrict__ km,
    const float* __restrict__ w_in, const float* __restrict__ b_in,
    const float* __restrict__ pos,
    const float* __restrict__ ln1g, const float* __restrict__ ln1b,
    const float* __restrict__ ln2g, const float* __restrict__ ln2b,
    const float* __restrict__ bq, const float* __restrict__ bk,
    const float* __restrict__ bv, const float* __restrict__ bo,
    const float* __restrict__ b1, const float* __restrict__ b2,
    const float* __restrict__ w_out, const float* __restrict__ b_out,
    const bf16* __restrict__ Wt, float* __restrict__ out)
{
    // LDS map. region0 (0..69632) is {T_bf,Q,K,Vt} during attn phases and
    // H[32][1024] during FFN (all four are dead there).
    __shared__ __align__(16) char L[110592];
    char* Tbf = L;                  // [32][256] bf16 swz
    char* Qb  = L + 16384;
    char* Kb  = L + 32768;
    char* Vt  = L + 49152;          // [256][40] ushort (d-major, m contiguous)
    char* Hb  = L;                  // [32][1024] bf16 swz (FFN phase)
    char* TnA = L + 69632;          // LN1-out / attn-O / LN2-out
    char* Pb  = L + 86016;          // 8 waves x [32][40] ushort
    float* red  = (float*)(L + 106496);
    float* red2 = (float*)(L + 108032);
    unsigned* kbits_p = (unsigned*)(L + 109568);

    int p = blockIdx.x;
    int tid = threadIdx.x;
    int wva = tid >> 6, ln = tid & 63;
    int c = ln & 15, g = ln >> 4;

    // 27-bit geometric window masks for this lane's two query tokens
    unsigned win0 = 0, win1 = 0;
    {
        int zq0 = c / 9, yq0 = (c / 3) % 3, xq0 = c % 3;
        int q1 = 16 + c, zq1 = q1 / 9, yq1 = (q1 / 3) % 3, xq1 = q1 % 3;
        for (int m = 0; m < 27; ++m) {
            int zm = m / 9, ym = (m / 3) % 3, xm = m % 3;
            if (abs(zm - zq0) <= 1 && abs(ym - yq0) <= 1 && abs(xm - xq0) <= 1) win0 |= 1u << m;
            if (q1 < 27 && abs(zm - zq1) <= 1 && abs(ym - yq1) <= 1 && abs(xm - xq1) <= 1) win1 |= 1u << m;
        }
    }
    if (tid < 64) {
        bool bit = (tid < 27) && (km[p * 27 + tid] != 0);
        unsigned long long bm = __ballot(bit);
        if (tid == 0) *kbits_p = (unsigned)(bm & 0x7FFFFFFull);
    }

    // ---- embed: residual t in regs (rows m*16+g*4+j, cols wva*32+n*16+c)
    float tr[2][2][4];
#pragma unroll
    for (int m = 0; m < 2; ++m)
#pragma unroll
    for (int j = 0; j < 4; ++j) {
        int row = m * 16 + g * 4 + j;
        float nv = (row < 27) ? npat[p * 27 + row] : 0.f;
#pragma unroll
        for (int n = 0; n < 2; ++n) {
            int col = wva * 32 + n * 16 + c;
            float v = 0.f;
            if (row < 27) v = nv * w_in[col] + b_in[col] + pos[row * DM + col];
            tr[m][n][j] = v;
            ldsW(Tbf, row, col, 512, v);
        }
    }

    f32x4 acc[2][2];
    float mu[2][4], rr[2][4];

    for (int l = 0; l < 3; ++l) {
        const bf16* wq  = Wt + (size_t)l * 786432;
        const bf16* wk  = wq + 65536;
        const bf16* wv2 = wk + 65536;
        const bf16* wo  = wv2 + 65536;
        const bf16* w1  = wo + 65536;
        const bf16* w2  = w1 + 262144;

        // ---- LN1 -> TnA
        ln_stats(tr, wva, c, g, red, red2, mu, rr);
#pragma unroll
        for (int m = 0; m < 2; ++m)
#pragma unroll
        for (int j = 0; j < 4; ++j) {
            int row = m * 16 + g * 4 + j;
#pragma unroll
            for (int n = 0; n < 2; ++n) {
                int col = wva * 32 + n * 16 + c;
                float v = (tr[m][n][j] - mu[m][j]) * rr[m][j] * ln1g[l * DM + col] + ln1b[l * DM + col];
                ldsW(TnA, row, col, 512, v);
            }
        }
        __syncthreads();

        // ---- Q, K, V projections (V stored transposed: Vt[d][m])
        zero_acc(acc);
        gemm32_acc<8, 512>(TnA, 0, wq, 256, 0, wva, c, g, acc);
#pragma unroll
        for (int m = 0; m < 2; ++m)
#pragma unroll
        for (int n = 0; n < 2; ++n) {
            int col = wva * 32 + n * 16 + c; float bb = bq[l * DM + col];
#pragma unroll
            for (int j = 0; j < 4; ++j) ldsW(Qb, m * 16 + g * 4 + j, col, 512, acc[m][n][j] + bb);
        }
        zero_acc(acc);
        gemm32_acc<8, 512>(Tbf, 0, wk, 256, 0, wva, c, g, acc);
#pragma unroll
        for (int m = 0; m < 2; ++m)
#pragma unroll
        for (int n = 0; n < 2; ++n) {
            int col = wva * 32 + n * 16 + c; float bb = bk[l * DM + col];
#pragma unroll
            for (int j = 0; j < 4; ++j) ldsW(Kb, m * 16 + g * 4 + j, col, 512, acc[m][n][j] + bb);
        }
        zero_acc(acc);
        gemm32_acc<8, 512>(Tbf, 0, wv2, 256, 0, wva, c, g, acc);
#pragma unroll
        for (int m = 0; m < 2; ++m)
#pragma unroll
        for (int n = 0; n < 2; ++n) {
            int col = wva * 32 + n * 16 + c; float bb = bv[l * DM + col];
#pragma unroll
            for (int j = 0; j < 4; ++j)
                *(unsigned short*)(Vt + col * 80 + (m * 16 + g * 4 + j) * 2) =
                    f2bf_bits(acc[m][n][j] + bb);
        }
        __syncthreads();

        // ---- attention: wave = head; S^T = K·Q^T; softmax lane-local; O=P·V
        {
            int h = wva;
            bf16x8 aK[2], bQ[2];
#pragma unroll
            for (int m = 0; m < 2; ++m) aK[m] = ldsA(Kb, m * 16 + c, h * 64 + g * 16, 512);
#pragma unroll
            for (int q = 0; q < 2; ++q) bQ[q] = ldsA(Qb, q * 16 + c, h * 64 + g * 16, 512);
            f32x4 sA[2][2];
#pragma unroll
            for (int at = 0; at < 2; ++at)
#pragma unroll
            for (int bt = 0; bt < 2; ++bt)
                sA[at][bt] = MFMA16(aK[at], bQ[bt], ((f32x4){0.f, 0.f, 0.f, 0.f}));

            unsigned kb = *kbits_p;
            unsigned Mq[2] = { kb & win0, kb & win1 };
            char* Pw = Pb + wva * 2560;
#pragma unroll
            for (int bt = 0; bt < 2; ++bt) {
                float e[2][4];
                float mx = -1e30f;
#pragma unroll
                for (int at = 0; at < 2; ++at)
#pragma unroll
                for (int rg = 0; rg < 4; ++rg) {
                    int m = at * 16 + g * 4 + rg;
                    bool in = (Mq[bt] >> m) & 1;
                    float sv = sA[at][bt][rg] * 0.17677669529663687f;
                    e[at][rg] = in ? sv : -1e30f;
                    mx = fmaxf(mx, e[at][rg]);
                }
                mx = fmaxf(mx, __shfl_xor(mx, 16));
                mx = fmaxf(mx, __shfl_xor(mx, 32));
                float sum = 0.f;
#pragma unroll
                for (int at = 0; at < 2; ++at)
#pragma unroll
                for (int rg = 0; rg < 4; ++rg) {
                    int m = at * 16 + g * 4 + rg;
                    bool in = (Mq[bt] >> m) & 1;
                    float ev = in ? expf(e[at][rg] - mx) : 0.f;
                    e[at][rg] = ev; sum += ev;
                }
                sum += __shfl_xor(sum, 16);
                sum += __shfl_xor(sum, 32);
                float inv = (sum > 0.f) ? 1.f / sum : 0.f;
#pragma unroll
                for (int at = 0; at < 2; ++at) {
                    ushort4 u;
                    u.x = f2bf_bits(e[at][0] * inv); u.y = f2bf_bits(e[at][1] * inv);
                    u.z = f2bf_bits(e[at][2] * inv); u.w = f2bf_bits(e[at][3] * inv);
                    *(ushort4*)(Pw + (bt * 16 + c) * 80 + (at * 16 + g * 4) * 2) = u;
                }
            }
            // PV (DS ops are in-order per wave: no barrier needed on Pw)
            bf16x8 pa[2], vb[2];
#pragma unroll
            for (int qt = 0; qt < 2; ++qt) pa[qt] = *(const bf16x8*)(Pw + (qt * 16 + c) * 80 + g * 16);
#pragma unroll
            for (int dt = 0; dt < 2; ++dt)
                vb[dt] = *(const bf16x8*)(Vt + (h * 32 + dt * 16 + c) * 80 + g * 16);
            f32x4 o[2][2];
#pragma unroll
            for (int qt = 0; qt < 2; ++qt)
#pragma unroll
            for (int dt = 0; dt < 2; ++dt)
                o[qt][dt] = MFMA16(pa[qt], vb[dt], ((f32x4){0.f, 0.f, 0.f, 0.f}));
#pragma unroll
            for (int qt = 0; qt < 2; ++qt)
#pragma unroll
            for (int dt = 0; dt < 2; ++dt)
#pragma unroll
            for (int rg = 0; rg < 4; ++rg)
                ldsW(TnA, qt * 16 + g * 4 + rg, h * 32 + dt * 16 + c, 512, o[qt][dt][rg]);
        }
        __syncthreads();

        // ---- Wo + residual into regs
        zero_acc(acc);
        gemm32_acc<8, 512>(TnA, 0, wo, 256, 0, wva, c, g, acc);
#pragma unroll
        for (int m = 0; m < 2; ++m)
#pragma unroll
        for (int n = 0; n < 2; ++n) {
            int col = wva * 32 + n * 16 + c; float bb = bo[l * DM + col];
#pragma unroll
            for (int j = 0; j < 4; ++j) tr[m][n][j] += acc[m][n][j] + bb;
        }

        // ---- LN2 -> TnA (internal syncthreads also fences Wo's TnA reads)
        ln_stats(tr, wva, c, g, red, red2, mu, rr);
#pragma unroll
        for (int m = 0; m < 2; ++m)
#pragma unroll
        for (int j = 0; j < 4; ++j) {
            int row = m * 16 + g * 4 + j;
#pragma unroll
            for (int n = 0; n < 2; ++n) {
                int col = wva * 32 + n * 16 + c;
                float v = (tr[m][n][j] - mu[m][j]) * rr[m][j] * ln2g[l * DM + col] + ln2b[l * DM + col];
                ldsW(TnA, row, col, 512, v);
            }
        }
        __syncthreads();

        // ---- FFN1: H = gelu(Tn2 @ W1 + b1); wave slice = 128 cols.
        // Double-banked W1 prefetch: load col-group n+1 while computing n.
        {
            f32x4 a8[2][8];
#pragma unroll
            for (int m = 0; m < 2; ++m)
#pragma unroll
            for (int n = 0; n < 8; ++n) a8[m][n] = (f32x4){0.f, 0.f, 0.f, 0.f};

            bf16x8 W1r[2][8];
#pragma unroll
            for (int ks = 0; ks < 8; ++ks)
                W1r[0][ks] = *(const bf16x8*)(w1 + (size_t)(wva * 128 + c) * 256 + ks * 32 + g * 8);
#pragma unroll
            for (int n = 0; n < 8; ++n) {
                if (n < 7) {
#pragma unroll
                    for (int ks = 0; ks < 8; ++ks)
                        W1r[(n + 1) & 1][ks] = *(const bf16x8*)(
                            w1 + (size_t)(wva * 128 + (n + 1) * 16 + c) * 256 + ks * 32 + g * 8);
                }
#pragma unroll
                for (int ks = 0; ks < 8; ++ks) {
                    bf16x8 a0 = ldsA(TnA, c,      ks * 64 + g * 16, 512);
                    bf16x8 a1 = ldsA(TnA, 16 + c, ks * 64 + g * 16, 512);
                    a8[0][n] = MFMA16(a0, W1r[n & 1][ks], a8[0][n]);
                    a8[1][n] = MFMA16(a1, W1r[n & 1][ks], a8[1][n]);
                }
            }
#pragma unroll
            for (int m = 0; m < 2; ++m)
#pragma unroll
            for (int n = 0; n < 8; ++n) {
                int col = wva * 128 + n * 16 + c;
                float bb = b1[l * FF + col];
#pragma unroll
                for (int j = 0; j < 4; ++j) {
                    float v = a8[m][n][j] + bb;
                    v = 0.5f * v * (1.0f + erff(v * 0.70710678118654752f));
                    ldsW(Hb, m * 16 + g * 4 + j, col, 2048, v);
                }
            }
        }
        __syncthreads();

        // ---- FFN2 + residual: K=1024 as 4 batched chunks of 256
        zero_acc(acc);
#pragma unroll
        for (int ch = 0; ch < 4; ++ch)
            gemm32_acc<8, 2048>(Hb, ch * 512, w2, 1024, ch * 256, wva, c, g, acc);
#pragma unroll
        for (int m = 0; m < 2; ++m)
#pragma unroll
        for (int n = 0; n < 2; ++n) {
            int col = wva * 32 + n * 16 + c; float bb = b2[l * DM + col];
#pragma unroll
            for (int j = 0; j < 4; ++j) tr[m][n][j] += acc[m][n][j] + bb;
        }
        __syncthreads();   // all waves done reading H before T_bf overwrite

        // refresh T_bf for next layer
#pragma unroll
        for (int m = 0; m < 2; ++m)
#pragma unroll
        for (int j = 0; j < 4; ++j) {
            int row = m * 16 + g * 4 + j;
#pragma unroll
            for (int n = 0; n < 2; ++n)
                ldsW(Tbf, row, wva * 32 + n * 16 + c, 512, tr[m][n][j]);
        }
        __syncthreads();
    }

    // ---- output: out[p] = t[13] . w_out + b_out   (row 13 = m0,g3,j1)
    float v = 0.f;
    if (g == 3) {
        v = tr[0][0][1] * w_out[wva * 32 + c] + tr[0][1][1] * w_out[wva * 32 + 16 + c];
    }
#pragma unroll
    for (int off = 1; off < 16; off <<= 1) v += __shfl_xor(v, off);
    if (ln == 48) red[wva] = v;
    __syncthreads();
    if (tid == 0) {
        float s = 0.f;
#pragma unroll
        for (int w = 0; w < 8; ++w) s += red[w];
        out[p] = s + b_out[0];
    }
}

// ---------------------------------------------------------------------------
extern "C" void kernel_launch(void* const* d_in, const int* in_sizes, int n_in,
                              void* d_out, int out_size, void* d_ws, size_t ws_size,
                              hipStream_t stream)
{
    const float* npat  = (const float*)d_in[0];
    const int*   kmask = (const int*)  d_in[1];
    const float* w_in  = (const float*)d_in[2];
    const float* b_in  = (const float*)d_in[3];
    const float* pos   = (const float*)d_in[4];
    const float* ln1_g = (const float*)d_in[5];
    const float* ln1_b = (const float*)d_in[6];
    const float* ln2_g = (const float*)d_in[7];
    const float* ln2_b = (const float*)d_in[8];
    const float* Wq    = (const float*)d_in[9];
    const float* bq    = (const float*)d_in[10];
    const float* Wk    = (const float*)d_in[11];
    const float* bk    = (const float*)d_in[12];
    const float* Wv    = (const float*)d_in[13];
    const float* bv    = (const float*)d_in[14];
    const float* Wo    = (const float*)d_in[15];
    const float* bo    = (const float*)d_in[16];
    const float* W1    = (const float*)d_in[17];
    const float* b1    = (const float*)d_in[18];
    const float* W2    = (const float*)d_in[19];
    const float* b2    = (const float*)d_in[20];
    const float* w_out = (const float*)d_in[21];
    const float* b_out = (const float*)d_in[22];
    float* out = (float*)d_out;

    bf16* Wt = (bf16*)d_ws;   // 3 * 786432 bf16 = 4.5 MB

    convert_weights<<<dim3(32, 32, 18), dim3(32, 8), 0, stream>>>(
        Wq, Wk, Wv, Wo, W1, W2, Wt);
    patch_net<<<256, 512, 0, stream>>>(
        npat, kmask, w_in, b_in, pos, ln1_g, ln1_b, ln2_g, ln2_b,
        bq, bk, bv, bo, b1, b2, w_out, b_out, Wt, out);
}

// Round 12
// 358.505 us; speedup vs baseline: 3.7886x; 1.1009x over previous
//
#include <hip/hip_runtime.h>
#include <hip/hip_bf16.h>

// ---------------------------------------------------------------------------
// IterativeVoxelModel R12: whole-network-per-patch kernel (R9/R11 structure)
// with ENFORCED batched weight prefetch: sched_barrier(0) after each load
// batch pins all loads before the MFMA cluster (R11 showed the scheduler
// re-serializes source-level batching: VGPR stayed 128, perf unchanged).
// FFN1 A-fragments hoisted to registers (ds_reads 128->16 per wave).
// ---------------------------------------------------------------------------

#define NTOK 6912
#define DM   256
#define FF   1024

typedef __hip_bfloat16 bf16;
typedef __bf16 bf16x8 __attribute__((ext_vector_type(8)));
typedef float  f32x4  __attribute__((ext_vector_type(4)));

#define MFMA16(a, b, c) __builtin_amdgcn_mfma_f32_16x16x32_bf16((a), (b), (c), 0, 0, 0)
#define SCHED_FENCE() __builtin_amdgcn_sched_barrier(0)

__device__ __forceinline__ unsigned short f2bf_bits(float x) {
    bf16 h = __float2bfloat16(x);
    union { bf16 h; unsigned short u; } u2; u2.h = h; return u2.u;
}

// row-major [32][rowB bytes] LDS buffer with XOR swizzle on 16B granules
__device__ __forceinline__ bf16x8 ldsA(const char* buf, int row, int kbyte, int rowB) {
    return *(const bf16x8*)(buf + row * rowB + (kbyte ^ ((row & 7) << 4)));
}
__device__ __forceinline__ void ldsW(char* buf, int row, int col, int rowB, float v) {
    *(unsigned short*)(buf + row * rowB + ((col * 2) ^ ((row & 7) << 4))) = f2bf_bits(v);
}

// ---------------- weight convert+transpose: W[K][N] f32 -> Wt[N][K] bf16 ---
__global__ __launch_bounds__(256) void convert_weights(
    const float* __restrict__ Wq, const float* __restrict__ Wk,
    const float* __restrict__ Wv, const float* __restrict__ Wo,
    const float* __restrict__ W1, const float* __restrict__ W2,
    bf16* __restrict__ Wt)
{
    __shared__ float tile[32][33];
    int id = blockIdx.z;
    int l = id / 6, wsel = id % 6;
    const float* src; bf16* dst; int K, N;
    if (wsel < 4) {
        const float* tbl[4] = {Wq, Wk, Wv, Wo};
        src = tbl[wsel] + (size_t)l * 65536; K = 256; N = 256;
        dst = Wt + (size_t)l * 786432 + wsel * 65536;
    } else if (wsel == 4) {
        src = W1 + (size_t)l * 262144; K = 256; N = 1024;
        dst = Wt + (size_t)l * 786432 + 262144;
    } else {
        src = W2 + (size_t)l * 262144; K = 1024; N = 256;
        dst = Wt + (size_t)l * 786432 + 524288;
    }
    int n0 = blockIdx.x * 32, k0 = blockIdx.y * 32;
    if (n0 >= N || k0 >= K) return;
    int tx = threadIdx.x, ty = threadIdx.y;   // 32 x 8
#pragma unroll
    for (int i = 0; i < 4; ++i)
        tile[ty + i * 8][tx] = src[(size_t)(k0 + ty + i * 8) * N + n0 + tx];
    __syncthreads();
#pragma unroll
    for (int i = 0; i < 4; ++i)
        dst[(size_t)(n0 + ty + i * 8) * K + k0 + tx] =
            __float2bfloat16(tile[tx][ty + i * 8]);
}

// ---- GEMM chunk: acc += A_lds[32 rows][32*NKS k] @ Bt-slice ---------------
// B fragments batch-loaded, then sched_barrier(0) pins them before the MFMA
// cluster: one exposed memory latency per chunk.
template<int NKS, int ROWB>
__device__ __forceinline__ void gemm32_acc(const char* A, int kbyte0,
    const bf16* __restrict__ Bt, int Krow, int k0,
    int wva, int c, int g, f32x4 acc[2][2])
{
    bf16x8 B0[NKS], B1[NKS];
#pragma unroll
    for (int ks = 0; ks < NKS; ++ks) {
        const bf16* bp = Bt + (size_t)(wva * 32 + c) * Krow + k0 + ks * 32 + g * 8;
        B0[ks] = *(const bf16x8*)bp;
        B1[ks] = *(const bf16x8*)(bp + (size_t)16 * Krow);
    }
    SCHED_FENCE();   // all 2*NKS loads issued before any MFMA below
#pragma unroll
    for (int ks = 0; ks < NKS; ++ks) {
        bf16x8 a0 = ldsA(A, c,      kbyte0 + ks * 64 + g * 16, ROWB);
        bf16x8 a1 = ldsA(A, 16 + c, kbyte0 + ks * 64 + g * 16, ROWB);
        acc[0][0] = MFMA16(a0, B0[ks], acc[0][0]);
        acc[0][1] = MFMA16(a0, B1[ks], acc[0][1]);
        acc[1][0] = MFMA16(a1, B0[ks], acc[1][0]);
        acc[1][1] = MFMA16(a1, B1[ks], acc[1][1]);
    }
}

__device__ __forceinline__ void zero_acc(f32x4 acc[2][2]) {
#pragma unroll
    for (int m = 0; m < 2; ++m)
#pragma unroll
        for (int n = 0; n < 2; ++n) acc[m][n] = (f32x4){0.f, 0.f, 0.f, 0.f};
}

// ---- LN row stats from register-resident residual ------------------------
__device__ __forceinline__ void ln_stats(const float tr[2][2][4], int wva, int c, int g,
                                         float* red, float* red2,
                                         float mu[2][4], float rr[2][4])
{
#pragma unroll
    for (int m = 0; m < 2; ++m)
#pragma unroll
    for (int j = 0; j < 4; ++j) {
        float s = tr[m][0][j] + tr[m][1][j];
        float q = tr[m][0][j] * tr[m][0][j] + tr[m][1][j] * tr[m][1][j];
#pragma unroll
        for (int off = 1; off < 16; off <<= 1) {
            s += __shfl_xor(s, off); q += __shfl_xor(q, off);
        }
        if (c == 0) { int row = m * 16 + g * 4 + j; red[row * 12 + wva] = s; red2[row * 12 + wva] = q; }
    }
    __syncthreads();
#pragma unroll
    for (int m = 0; m < 2; ++m)
#pragma unroll
    for (int j = 0; j < 4; ++j) {
        int row = m * 16 + g * 4 + j;
        float S = 0.f, Q = 0.f;
#pragma unroll
        for (int w = 0; w < 8; ++w) { S += red[row * 12 + w]; Q += red2[row * 12 + w]; }
        float m_ = S * (1.0f / DM);
        float v_ = Q * (1.0f / DM) - m_ * m_;
        mu[m][j] = m_; rr[m][j] = rsqrtf(v_ + 1e-5f);
    }
}

// ---------------------------------------------------------------------------
__global__ __launch_bounds__(512, 2) void patch_net(
    const float* __restrict__ npat, const int* __restrict__ km,
    const float* __restrict__ w_in, const float* __restrict__ b_in,
    const float* __restrict__ pos,
    const float* __restrict__ ln1g, const float* __restrict__ ln1b,
    const float* __restrict__ ln2g, const float* __restrict__ ln2b,
    const float* __restrict__ bq, const float* __restrict__ bk,
    const float* __restrict__ bv, const float* __restrict__ bo,
    const float* __restrict__ b1, const float* __restrict__ b2,
    const float* __restrict__ w_out, const float* __restrict__ b_out,
    const bf16* __restrict__ Wt, float* __restrict__ out)
{
    // LDS map. region0 (0..69632) is {T_bf,Q,K,Vt} during attn phases and
    // H[32][1024] during FFN (all four are dead there).
    __shared__ __align__(16) char L[110592];
    char* Tbf = L;                  // [32][256] bf16 swz
    char* Qb  = L + 16384;
    char* Kb  = L + 32768;
    char* Vt  = L + 49152;          // [256][40] ushort (d-major, m contiguous)
    char* Hb  = L;                  // [32][1024] bf16 swz (FFN phase)
    char* TnA = L + 69632;          // LN1-out / attn-O / LN2-out
    char* Pb  = L + 86016;          // 8 waves x [32][40] ushort
    float* red  = (float*)(L + 106496);
    float* red2 = (float*)(L + 108032);
    unsigned* kbits_p = (unsigned*)(L + 109568);

    int p = blockIdx.x;
    int tid = threadIdx.x;
    int wva = tid >> 6, ln = tid & 63;
    int c = ln & 15, g = ln >> 4;

    // 27-bit geometric window masks for this lane's two query tokens
    unsigned win0 = 0, win1 = 0;
    {
        int zq0 = c / 9, yq0 = (c / 3) % 3, xq0 = c % 3;
        int q1 = 16 + c, zq1 = q1 / 9, yq1 = (q1 / 3) % 3, xq1 = q1 % 3;
        for (int m = 0; m < 27; ++m) {
            int zm = m / 9, ym = (m / 3) % 3, xm = m % 3;
            if (abs(zm - zq0) <= 1 && abs(ym - yq0) <= 1 && abs(xm - xq0) <= 1) win0 |= 1u << m;
            if (q1 < 27 && abs(zm - zq1) <= 1 && abs(ym - yq1) <= 1 && abs(xm - xq1) <= 1) win1 |= 1u << m;
        }
    }
    if (tid < 64) {
        bool bit = (tid < 27) && (km[p * 27 + tid] != 0);
        unsigned long long bm = __ballot(bit);
        if (tid == 0) *kbits_p = (unsigned)(bm & 0x7FFFFFFull);
    }

    // ---- embed: residual t in regs (rows m*16+g*4+j, cols wva*32+n*16+c)
    float tr[2][2][4];
#pragma unroll
    for (int m = 0; m < 2; ++m)
#pragma unroll
    for (int j = 0; j < 4; ++j) {
        int row = m * 16 + g * 4 + j;
        float nv = (row < 27) ? npat[p * 27 + row] : 0.f;
#pragma unroll
        for (int n = 0; n < 2; ++n) {
            int col = wva * 32 + n * 16 + c;
            float v = 0.f;
            if (row < 27) v = nv * w_in[col] + b_in[col] + pos[row * DM + col];
            tr[m][n][j] = v;
            ldsW(Tbf, row, col, 512, v);
        }
    }

    f32x4 acc[2][2];
    float mu[2][4], rr[2][4];

    for (int l = 0; l < 3; ++l) {
        const bf16* wq  = Wt + (size_t)l * 786432;
        const bf16* wk  = wq + 65536;
        const bf16* wv2 = wk + 65536;
        const bf16* wo  = wv2 + 65536;
        const bf16* w1  = wo + 65536;
        const bf16* w2  = w1 + 262144;

        // ---- LN1 -> TnA
        ln_stats(tr, wva, c, g, red, red2, mu, rr);
#pragma unroll
        for (int m = 0; m < 2; ++m)
#pragma unroll
        for (int j = 0; j < 4; ++j) {
            int row = m * 16 + g * 4 + j;
#pragma unroll
            for (int n = 0; n < 2; ++n) {
                int col = wva * 32 + n * 16 + c;
                float v = (tr[m][n][j] - mu[m][j]) * rr[m][j] * ln1g[l * DM + col] + ln1b[l * DM + col];
                ldsW(TnA, row, col, 512, v);
            }
        }
        __syncthreads();

        // ---- Q, K, V projections (V stored transposed: Vt[d][m])
        zero_acc(acc);
        gemm32_acc<8, 512>(TnA, 0, wq, 256, 0, wva, c, g, acc);
#pragma unroll
        for (int m = 0; m < 2; ++m)
#pragma unroll
        for (int n = 0; n < 2; ++n) {
            int col = wva * 32 + n * 16 + c; float bb = bq[l * DM + col];
#pragma unroll
            for (int j = 0; j < 4; ++j) ldsW(Qb, m * 16 + g * 4 + j, col, 512, acc[m][n][j] + bb);
        }
        zero_acc(acc);
        gemm32_acc<8, 512>(Tbf, 0, wk, 256, 0, wva, c, g, acc);
#pragma unroll
        for (int m = 0; m < 2; ++m)
#pragma unroll
        for (int n = 0; n < 2; ++n) {
            int col = wva * 32 + n * 16 + c; float bb = bk[l * DM + col];
#pragma unroll
            for (int j = 0; j < 4; ++j) ldsW(Kb, m * 16 + g * 4 + j, col, 512, acc[m][n][j] + bb);
        }
        zero_acc(acc);
        gemm32_acc<8, 512>(Tbf, 0, wv2, 256, 0, wva, c, g, acc);
#pragma unroll
        for (int m = 0; m < 2; ++m)
#pragma unroll
        for (int n = 0; n < 2; ++n) {
            int col = wva * 32 + n * 16 + c; float bb = bv[l * DM + col];
#pragma unroll
            for (int j = 0; j < 4; ++j)
                *(unsigned short*)(Vt + col * 80 + (m * 16 + g * 4 + j) * 2) =
                    f2bf_bits(acc[m][n][j] + bb);
        }
        // NO __syncthreads here: attention wave h reads exactly the LDS
        // columns written by wave h (head slice == wave col slice), and DS
        // ops are in-order within a wave.

        // ---- attention: wave = head; S^T = K·Q^T; softmax lane-local; O=P·V
        {
            int h = wva;
            bf16x8 aK[2], bQ[2];
#pragma unroll
            for (int m = 0; m < 2; ++m) aK[m] = ldsA(Kb, m * 16 + c, h * 64 + g * 16, 512);
#pragma unroll
            for (int q = 0; q < 2; ++q) bQ[q] = ldsA(Qb, q * 16 + c, h * 64 + g * 16, 512);
            f32x4 sA[2][2];
#pragma unroll
            for (int at = 0; at < 2; ++at)
#pragma unroll
            for (int bt = 0; bt < 2; ++bt)
                sA[at][bt] = MFMA16(aK[at], bQ[bt], ((f32x4){0.f, 0.f, 0.f, 0.f}));

            unsigned kb = *kbits_p;
            unsigned Mq[2] = { kb & win0, kb & win1 };
            char* Pw = Pb + wva * 2560;
#pragma unroll
            for (int bt = 0; bt < 2; ++bt) {
                float e[2][4];
                float mx = -1e30f;
#pragma unroll
                for (int at = 0; at < 2; ++at)
#pragma unroll
                for (int rg = 0; rg < 4; ++rg) {
                    int m = at * 16 + g * 4 + rg;
                    bool in = (Mq[bt] >> m) & 1;
                    float sv = sA[at][bt][rg] * 0.17677669529663687f;
                    e[at][rg] = in ? sv : -1e30f;
                    mx = fmaxf(mx, e[at][rg]);
                }
                mx = fmaxf(mx, __shfl_xor(mx, 16));
                mx = fmaxf(mx, __shfl_xor(mx, 32));
                float sum = 0.f;
#pragma unroll
                for (int at = 0; at < 2; ++at)
#pragma unroll
                for (int rg = 0; rg < 4; ++rg) {
                    int m = at * 16 + g * 4 + rg;
                    bool in = (Mq[bt] >> m) & 1;
                    float ev = in ? expf(e[at][rg] - mx) : 0.f;
                    e[at][rg] = ev; sum += ev;
                }
                sum += __shfl_xor(sum, 16);
                sum += __shfl_xor(sum, 32);
                float inv = (sum > 0.f) ? 1.f / sum : 0.f;
#pragma unroll
                for (int at = 0; at < 2; ++at) {
                    ushort4 u;
                    u.x = f2bf_bits(e[at][0] * inv); u.y = f2bf_bits(e[at][1] * inv);
                    u.z = f2bf_bits(e[at][2] * inv); u.w = f2bf_bits(e[at][3] * inv);
                    *(ushort4*)(Pw + (bt * 16 + c) * 80 + (at * 16 + g * 4) * 2) = u;
                }
            }
            // PV (DS ops are in-order per wave: no barrier needed on Pw)
            bf16x8 pa[2], vb[2];
#pragma unroll
            for (int qt = 0; qt < 2; ++qt) pa[qt] = *(const bf16x8*)(Pw + (qt * 16 + c) * 80 + g * 16);
#pragma unroll
            for (int dt = 0; dt < 2; ++dt)
                vb[dt] = *(const bf16x8*)(Vt + (h * 32 + dt * 16 + c) * 80 + g * 16);
            f32x4 o[2][2];
#pragma unroll
            for (int qt = 0; qt < 2; ++qt)
#pragma unroll
            for (int dt = 0; dt < 2; ++dt)
                o[qt][dt] = MFMA16(pa[qt], vb[dt], ((f32x4){0.f, 0.f, 0.f, 0.f}));
#pragma unroll
            for (int qt = 0; qt < 2; ++qt)
#pragma unroll
            for (int dt = 0; dt < 2; ++dt)
#pragma unroll
            for (int rg = 0; rg < 4; ++rg)
                ldsW(TnA, qt * 16 + g * 4 + rg, h * 32 + dt * 16 + c, 512, o[qt][dt][rg]);
        }
        __syncthreads();   // Wo reads all TnA columns -> cross-wave

        // ---- Wo + residual into regs
        zero_acc(acc);
        gemm32_acc<8, 512>(TnA, 0, wo, 256, 0, wva, c, g, acc);
#pragma unroll
        for (int m = 0; m < 2; ++m)
#pragma unroll
        for (int n = 0; n < 2; ++n) {
            int col = wva * 32 + n * 16 + c; float bb = bo[l * DM + col];
#pragma unroll
            for (int j = 0; j < 4; ++j) tr[m][n][j] += acc[m][n][j] + bb;
        }

        // ---- LN2 -> TnA (internal syncthreads also fences Wo's TnA reads)
        ln_stats(tr, wva, c, g, red, red2, mu, rr);
#pragma unroll
        for (int m = 0; m < 2; ++m)
#pragma unroll
        for (int j = 0; j < 4; ++j) {
            int row = m * 16 + g * 4 + j;
#pragma unroll
            for (int n = 0; n < 2; ++n) {
                int col = wva * 32 + n * 16 + c;
                float v = (tr[m][n][j] - mu[m][j]) * rr[m][j] * ln2g[l * DM + col] + ln2b[l * DM + col];
                ldsW(TnA, row, col, 512, v);
            }
        }
        __syncthreads();

        // ---- FFN1: H = gelu(Tn2 @ W1 + b1); wave slice = 128 cols.
        // A-fragments hoisted once (16 ds_reads instead of 128); per-n
        // 8-load batch pinned by sched_barrier, MFMA+GELU epilogue covers
        // the next batch's latency.
        {
            bf16x8 A0[8], A1[8];
#pragma unroll
            for (int ks = 0; ks < 8; ++ks) {
                A0[ks] = ldsA(TnA, c,      ks * 64 + g * 16, 512);
                A1[ks] = ldsA(TnA, 16 + c, ks * 64 + g * 16, 512);
            }
#pragma unroll
            for (int n = 0; n < 8; ++n) {
                bf16x8 Wn[8];
#pragma unroll
                for (int ks = 0; ks < 8; ++ks)
                    Wn[ks] = *(const bf16x8*)(
                        w1 + (size_t)(wva * 128 + n * 16 + c) * 256 + ks * 32 + g * 8);
                SCHED_FENCE();
                f32x4 h0 = (f32x4){0.f, 0.f, 0.f, 0.f};
                f32x4 h1 = (f32x4){0.f, 0.f, 0.f, 0.f};
#pragma unroll
                for (int ks = 0; ks < 8; ++ks) {
                    h0 = MFMA16(A0[ks], Wn[ks], h0);
                    h1 = MFMA16(A1[ks], Wn[ks], h1);
                }
                int col = wva * 128 + n * 16 + c;
                float bb = b1[l * FF + col];
#pragma unroll
                for (int j = 0; j < 4; ++j) {
                    float v0 = h0[j] + bb;
                    v0 = 0.5f * v0 * (1.0f + erff(v0 * 0.70710678118654752f));
                    ldsW(Hb, g * 4 + j, col, 2048, v0);
                    float v1 = h1[j] + bb;
                    v1 = 0.5f * v1 * (1.0f + erff(v1 * 0.70710678118654752f));
                    ldsW(Hb, 16 + g * 4 + j, col, 2048, v1);
                }
            }
        }
        __syncthreads();

        // ---- FFN2 + residual: K=1024 as 4 pinned-batch chunks of 256
        zero_acc(acc);
#pragma unroll
        for (int ch = 0; ch < 4; ++ch)
            gemm32_acc<8, 2048>(Hb, ch * 512, w2, 1024, ch * 256, wva, c, g, acc);
#pragma unroll
        for (int m = 0; m < 2; ++m)
#pragma unroll
        for (int n = 0; n < 2; ++n) {
            int col = wva * 32 + n * 16 + c; float bb = b2[l * DM + col];
#pragma unroll
            for (int j = 0; j < 4; ++j) tr[m][n][j] += acc[m][n][j] + bb;
        }
        __syncthreads();   // all waves done reading H before T_bf overwrite

        // refresh T_bf for next layer
#pragma unroll
        for (int m = 0; m < 2; ++m)
#pragma unroll
        for (int j = 0; j < 4; ++j) {
            int row = m * 16 + g * 4 + j;
#pragma unroll
            for (int n = 0; n < 2; ++n)
                ldsW(Tbf, row, wva * 32 + n * 16 + c, 512, tr[m][n][j]);
        }
        __syncthreads();
    }

    // ---- output: out[p] = t[13] . w_out + b_out   (row 13 = m0,g3,j1)
    float v = 0.f;
    if (g == 3) {
        v = tr[0][0][1] * w_out[wva * 32 + c] + tr[0][1][1] * w_out[wva * 32 + 16 + c];
    }
#pragma unroll
    for (int off = 1; off < 16; off <<= 1) v += __shfl_xor(v, off);
    if (ln == 48) red[wva] = v;
    __syncthreads();
    if (tid == 0) {
        float s = 0.f;
#pragma unroll
        for (int w = 0; w < 8; ++w) s += red[w];
        out[p] = s + b_out[0];
    }
}

// ---------------------------------------------------------------------------
extern "C" void kernel_launch(void* const* d_in, const int* in_sizes, int n_in,
                              void* d_out, int out_size, void* d_ws, size_t ws_size,
                              hipStream_t stream)
{
    const float* npat  = (const float*)d_in[0];
    const int*   kmask = (const int*)  d_in[1];
    const float* w_in  = (const float*)d_in[2];
    const float* b_in  = (const float*)d_in[3];
    const float* pos   = (const float*)d_in[4];
    const float* ln1_g = (const float*)d_in[5];
    const float* ln1_b = (const float*)d_in[6];
    const float* ln2_g = (const float*)d_in[7];
    const float* ln2_b = (const float*)d_in[8];
    const float* Wq    = (const float*)d_in[9];
    const float* bq    = (const float*)d_in[10];
    const float* Wk    = (const float*)d_in[11];
    const float* bk    = (const float*)d_in[12];
    const float* Wv    = (const float*)d_in[13];
    const float* bv    = (const float*)d_in[14];
    const float* Wo    = (const float*)d_in[15];
    const float* bo    = (const float*)d_in[16];
    const float* W1    = (const float*)d_in[17];
    const float* b1    = (const float*)d_in[18];
    const float* W2    = (const float*)d_in[19];
    const float* b2    = (const float*)d_in[20];
    const float* w_out = (const float*)d_in[21];
    const float* b_out = (const float*)d_in[22];
    float* out = (float*)d_out;

    bf16* Wt = (bf16*)d_ws;   // 3 * 786432 bf16 = 4.5 MB

    convert_weights<<<dim3(32, 32, 18), dim3(32, 8), 0, stream>>>(
        Wq, Wk, Wv, Wo, W1, W2, Wt);
    patch_net<<<256, 512, 0, stream>>>(
        npat, kmask, w_in, b_in, pos, ln1_g, ln1_b, ln2_g, ln2_b,
        bq, bk, bv, bo, b1, b2, w_out, b_out, Wt, out);
}